// Round 1
// 196.139 us; speedup vs baseline: 1.1027x; 1.1027x over previous
//
#include <hip/hip_runtime.h>

#define T_TOKENS 2048
#define N_EXPERTS 8
#define ROWS (T_TOKENS * 2)      // T * TOPK
#define I_DIM 2048
#define H_DIM 1024

#define M_TILE 64
#define N_TILE 128
#define BK 64
#define KSPLIT 2
#define KCHUNK (I_DIM / KSPLIT)  // 1024

typedef __bf16 bf16x8 __attribute__((ext_vector_type(8)));
typedef float f32x4 __attribute__((ext_vector_type(4)));

__device__ inline void load_lds16(const void* g, void* l) {
    // lane i's 16B land at (wave-uniform) l + i*16; global src is per-lane
    __builtin_amdgcn_global_load_lds(
        (const __attribute__((address_space(1))) void*)g,
        (__attribute__((address_space(3))) void*)l, 16, 0, 0);
}

// Fused prep, one dispatch:
//  blocks [0,2048):    w [E][K][N] fp32 -> wT [E][N][K] bf16 (128k x 64n tiles,
//                      256B segments both sides, LDS pitch 65)
//  blocks [2048,4096): x fp32 -> xB bf16 streaming convert
//  blocks [4096,5120): zero out (+ cnt in block 4096)
__global__ __launch_bounds__(256) void prep_kernel(
    const float* __restrict__ w, const float* __restrict__ x,
    __bf16* __restrict__ wT, __bf16* __restrict__ xB,
    float* __restrict__ out, int* __restrict__ cnt) {
    const int b = blockIdx.x;
    const int t = threadIdx.x;
    if (b < 2048) {
        __shared__ float tile[128 * 65];   // pitch 65: col reads <=4-way
        const int e = b >> 8;              // 256 blocks/expert = 16 ktiles*16 ntiles
        const int k0 = ((b >> 4) & 15) * 128;
        const int n0 = (b & 15) * 64;
        const float* ws = w + (size_t)e * (I_DIM * H_DIM) + (size_t)k0 * H_DIM + n0;
#pragma unroll
        for (int i = 0; i < 8; ++i) {
            int flat = i * 256 + t;
            int k = flat >> 4, nq = (flat & 15) * 4;   // 16 lanes = 256B contiguous
            f32x4 v = *(const f32x4*)(ws + (size_t)k * H_DIM + nq);
            float* d = &tile[k * 65 + nq];
            d[0] = v.x; d[1] = v.y; d[2] = v.z; d[3] = v.w;
        }
        __syncthreads();
        __bf16* wd = wT + (size_t)e * (H_DIM * I_DIM) + (size_t)n0 * I_DIM + k0;
#pragma unroll
        for (int j = 0; j < 4; ++j) {
            int flat = j * 256 + t;
            int n = flat >> 4, kc = (flat & 15) * 8;   // 16 lanes = 256B contiguous
            bf16x8 o;
#pragma unroll
            for (int q = 0; q < 8; ++q) o[q] = (__bf16)tile[(kc + q) * 65 + n];
            *(bf16x8*)(wd + (size_t)n * I_DIM + kc) = o;
        }
    } else if (b < 4096) {
        // 2048 blocks * 256 thr * 16 elems = 8M = ROWS*I_DIM
        size_t base = ((size_t)(b - 2048) * 256 + t) * 16;
        const f32x4* xs = (const f32x4*)(x + base);
        f32x4 v0 = xs[0], v1 = xs[1], v2 = xs[2], v3 = xs[3];
        bf16x8 o0 = { (__bf16)v0.x, (__bf16)v0.y, (__bf16)v0.z, (__bf16)v0.w,
                      (__bf16)v1.x, (__bf16)v1.y, (__bf16)v1.z, (__bf16)v1.w };
        bf16x8 o1 = { (__bf16)v2.x, (__bf16)v2.y, (__bf16)v2.z, (__bf16)v2.w,
                      (__bf16)v3.x, (__bf16)v3.y, (__bf16)v3.z, (__bf16)v3.w };
        *(bf16x8*)(xB + base) = o0;
        *(bf16x8*)(xB + base + 8) = o1;
    } else {
        // 1024 blocks * 256 thr * 8 floats = 2M = T_TOKENS*H_DIM
        size_t idx = (size_t)(b - 4096) * 256 + t;
        f32x4 z = (f32x4){0.f, 0.f, 0.f, 0.f};
        ((f32x4*)out)[2 * idx] = z;
        ((f32x4*)out)[2 * idx + 1] = z;
        if (b == 4096 && t < N_EXPERTS) cnt[t] = 0;
    }
}

// One thread per token: softmax over 8 logits, top-2 (strict '>' keeps lower index
// first on ties, matching jax.lax.top_k), append rows to per-expert lists.
__global__ void routing_kernel(const float* __restrict__ logits,
                               float* __restrict__ topk_w,
                               int* __restrict__ cnt,
                               int* __restrict__ rowlist) {
    int t = blockIdx.x * blockDim.x + threadIdx.x;
    if (t >= T_TOKENS) return;
    float l[8];
#pragma unroll
    for (int e = 0; e < 8; ++e) l[e] = logits[t * 8 + e];
    float mx = l[0];
#pragma unroll
    for (int e = 1; e < 8; ++e) mx = fmaxf(mx, l[e]);
    float s = 0.f;
#pragma unroll
    for (int e = 0; e < 8; ++e) { l[e] = expf(l[e] - mx); s += l[e]; }
    float inv = 1.f / s;
    float v0 = -1.f, v1 = -1.f; int i0 = 0, i1 = 0;
#pragma unroll
    for (int e = 0; e < 8; ++e) {
        float p = l[e] * inv;
        if (p > v0)      { v1 = v0; i1 = i0; v0 = p; i0 = e; }
        else if (p > v1) { v1 = p; i1 = e; }
    }
    topk_w[2 * t]     = v0;
    topk_w[2 * t + 1] = v1;
    int p0 = atomicAdd(&cnt[i0], 1); rowlist[i0 * ROWS + p0] = 2 * t;
    int p1 = atomicAdd(&cnt[i1], 1); rowlist[i1 * ROWS + p1] = 2 * t + 1;
}

// Grouped expert GEMM, 64x128 tile, BK=64, bf16 MFMA 16x16x32.
// Both A (xB, rowlist-gathered) and B (wT) staged via global_load_lds DMA into
// XOR-swizzled LDS (rule 21: linear LDS dest + inverse-swizzled GLOBAL source
// chunk + same XOR on the fragment-read address). Swizzle is a permutation of
// the 8x16B chunks within each 128B row -> coalescing preserved, frag reads
// become 2-way (free) instead of 8-way bank-conflicted.
__global__ __launch_bounds__(256, 4) void gemm_kernel(
    const __bf16* __restrict__ xB, const __bf16* __restrict__ wT,
    const int* __restrict__ cnt, const int* __restrict__ rowlist,
    const float* __restrict__ topk_w, float* __restrict__ out) {
    const int e = blockIdx.y;
    const int cnt_e = cnt[e];
    const int m0 = blockIdx.z * M_TILE;
    if (m0 >= cnt_e) return;
    const int ntile = blockIdx.x & 7;
    const int khalf = blockIdx.x >> 3;
    const int n0 = ntile * N_TILE;
    const int tid = threadIdx.x;
    const int lane = tid & 63;
    const int wave = tid >> 6;
    const int wm = wave & 1, wn = wave >> 1;

    // row-major LDS: A [64 rows][64 bf16] (128 B/row), B [128 rows][64 bf16]
    __shared__ __bf16 As[M_TILE * BK];   //  8 KB
    __shared__ __bf16 Bs[N_TILE * BK];   // 16 KB

    const int* rl = rowlist + e * ROWS;

    const int lc = lane & 7;    // 16B chunk within a 128B row
    const int lr = lane >> 3;   // row within an 8-row DMA group
    const int cg = lc ^ lr;     // inverse-swizzled global chunk (row&7 == lr)

    // A: 2 DMA instrs/wave cover rows 16w..16w+15 (gathered via rowlist)
    const int ar0 = 16 * wave + lr;
    int gm0 = m0 + ar0;     if (gm0 >= cnt_e) gm0 = cnt_e - 1;  // dup row, dropped in epilogue
    int gm1 = m0 + ar0 + 8; if (gm1 >= cnt_e) gm1 = cnt_e - 1;
    const __bf16* asrc0 = xB + (size_t)rl[gm0] * I_DIM + khalf * KCHUNK + cg * 8;
    const __bf16* asrc1 = xB + (size_t)rl[gm1] * I_DIM + khalf * KCHUNK + cg * 8;
    __bf16* adst0 = As + 1024 * wave;          // rows 16w..16w+7 (linear)
    __bf16* adst1 = As + 1024 * wave + 512;    // rows 16w+8..16w+15

    // B: 4 DMA instrs/wave cover n-rows 32w..32w+31
    const int br = 32 * wave + lr;
    const __bf16* wTe = wT + (size_t)e * (H_DIM * I_DIM);
    const __bf16* bsrc = wTe + (size_t)(n0 + br) * I_DIM + khalf * KCHUNK + cg * 8;
    __bf16* bdst = Bs + 2048 * wave;

    // fragment-read offsets (elements), swizzled with the same XOR:
    // row m|n = {wm*32|wn*64} + t*16 + lm  ->  (m&7) == (lm&7)
    const int lm = lane & 15, lg = lane >> 4, sw = lm & 7;
    int offA[2][2], offB[2][4];
#pragma unroll
    for (int s = 0; s < 2; ++s) {
        int cs = (((s * 4) + lg) ^ sw) * 8;
#pragma unroll
        for (int mt = 0; mt < 2; ++mt)
            offA[s][mt] = (wm * 32 + mt * 16 + lm) * BK + cs;
#pragma unroll
        for (int nt = 0; nt < 4; ++nt)
            offB[s][nt] = (wn * 64 + nt * 16 + lm) * BK + cs;
    }

    f32x4 acc[2][4];
#pragma unroll
    for (int mt = 0; mt < 2; ++mt)
#pragma unroll
        for (int nt = 0; nt < 4; ++nt)
            acc[mt][nt] = (f32x4){0.f, 0.f, 0.f, 0.f};

    for (int ks = 0; ks < KCHUNK; ks += BK) {
        __syncthreads();                 // LDS safe to overwrite
        load_lds16(asrc0, adst0);
        load_lds16(asrc1, adst1);
        load_lds16(bsrc,              bdst);
        load_lds16(bsrc +  8 * I_DIM, bdst + 512);
        load_lds16(bsrc + 16 * I_DIM, bdst + 1024);
        load_lds16(bsrc + 24 * I_DIM, bdst + 1536);
        asrc0 += BK; asrc1 += BK; bsrc += BK;
        __syncthreads();                 // drains DMA (vmcnt) before compute

#pragma unroll
        for (int s = 0; s < 2; ++s) {
            bf16x8 a0 = *(const bf16x8*)&As[offA[s][0]];
            bf16x8 a1 = *(const bf16x8*)&As[offA[s][1]];
            bf16x8 b0 = *(const bf16x8*)&Bs[offB[s][0]];
            bf16x8 b1 = *(const bf16x8*)&Bs[offB[s][1]];
            bf16x8 b2 = *(const bf16x8*)&Bs[offB[s][2]];
            bf16x8 b3 = *(const bf16x8*)&Bs[offB[s][3]];
            acc[0][0] = __builtin_amdgcn_mfma_f32_16x16x32_bf16(a0, b0, acc[0][0], 0, 0, 0);
            acc[0][1] = __builtin_amdgcn_mfma_f32_16x16x32_bf16(a0, b1, acc[0][1], 0, 0, 0);
            acc[0][2] = __builtin_amdgcn_mfma_f32_16x16x32_bf16(a0, b2, acc[0][2], 0, 0, 0);
            acc[0][3] = __builtin_amdgcn_mfma_f32_16x16x32_bf16(a0, b3, acc[0][3], 0, 0, 0);
            acc[1][0] = __builtin_amdgcn_mfma_f32_16x16x32_bf16(a1, b0, acc[1][0], 0, 0, 0);
            acc[1][1] = __builtin_amdgcn_mfma_f32_16x16x32_bf16(a1, b1, acc[1][1], 0, 0, 0);
            acc[1][2] = __builtin_amdgcn_mfma_f32_16x16x32_bf16(a1, b2, acc[1][2], 0, 0, 0);
            acc[1][3] = __builtin_amdgcn_mfma_f32_16x16x32_bf16(a1, b3, acc[1][3], 0, 0, 0);
        }
    }

    // epilogue: C/D col=lane&15, row=(lane>>4)*4+reg; scale by topk weight,
    // atomicAdd into out[token] (covers topk-sum and K-split sum)
    const int lq = lane >> 4, ln = lane & 15;
#pragma unroll
    for (int mt = 0; mt < 2; ++mt) {
#pragma unroll
        for (int j = 0; j < 4; ++j) {
            int gm = m0 + wm * 32 + mt * 16 + lq * 4 + j;
            if (gm < cnt_e) {
                int row = rl[gm];
                float tw = topk_w[row];
                float* orow = out + (size_t)(row >> 1) * H_DIM + n0 + wn * 64 + ln;
#pragma unroll
                for (int nt = 0; nt < 4; ++nt)
                    atomicAdd(&orow[nt * 16], acc[mt][nt][j] * tw);
            }
        }
    }
}

extern "C" void kernel_launch(void* const* d_in, const int* in_sizes, int n_in,
                              void* d_out, int out_size, void* d_ws, size_t ws_size,
                              hipStream_t stream) {
    const float* x      = (const float*)d_in[0];  // [ROWS, I_DIM] fp32
    const float* w      = (const float*)d_in[1];  // [E, I_DIM, H_DIM] fp32
    const float* logits = (const float*)d_in[2];  // [T, E] fp32
    float* out = (float*)d_out;                   // [T, H_DIM] fp32

    char* ws = (char*)d_ws;
    float*  topk_w  = (float*)ws;                                      // 16 KB
    int*    cnt     = (int*)(ws + 16384);                              // 128 B
    int*    rowlist = (int*)(ws + 16384 + 128);                        // 128 KB
    __bf16* wT      = (__bf16*)(ws + 16384 + 128 + 131072);            // 32 MB [E][H][I]
    __bf16* xB      = (__bf16*)(ws + 16384 + 128 + 131072 + 33554432); // 16 MB [ROWS][I]

    // prep: w transpose+convert (2048) + x convert (2048) + out/cnt zero (1024)
    prep_kernel<<<5120, 256, 0, stream>>>(w, x, wT, xB, out, cnt);
    routing_kernel<<<T_TOKENS / 256, 256, 0, stream>>>(logits, topk_w, cnt, rowlist);
    // x = ntile+khalf (all active), y = expert, z = m-tile (early-exit tail)
    gemm_kernel<<<dim3((H_DIM / N_TILE) * KSPLIT, N_EXPERTS, ROWS / M_TILE), 256, 0, stream>>>(
        xB, wT, cnt, rowlist, topk_w, out);
}